// Round 2
// baseline (28.521 us; speedup 1.0000x reference)
//
#include <hip/hip_runtime.h>

// Problem constants (shapes fixed by setup_inputs).
#define NCLASSES 5
#define MS 8
#define NC 128          // channels
#define HW (256 * 256)  // H*W

// Per pixel: out[m] = relu( dot(image[b,:,h,w], W[l,m,:]) + b[l,m] ), l = cluster label.
// W staged in LDS as [c][l][m] so the 8 m-values for (c,l) are one 32B-aligned float8
// (2x ds_read_b128). Lanes sharing a label broadcast the same LDS address (free).
__global__ __launch_bounds__(256, 4) void clusterdown_kernel(
    const float* __restrict__ image,      // (B, C, H, W)
    const int* __restrict__ clusters,     // (B, 1, H, W) — harness passes integers as int32
    const float* __restrict__ Wg,         // (NCLASSES, MS, NC)
    const float* __restrict__ bg,         // (NCLASSES, MS)
    float* __restrict__ out,              // (B, MS, H, W)
    int n_pix)                            // B*H*W
{
    __shared__ float wlds[NC * NCLASSES * MS]; // 5120 floats = 20 KiB, [c][l][m]
    __shared__ float blds[NCLASSES * MS];

    const int tid = threadIdx.x;

    // Stage W: Wg[(l*MS+m)*NC + c] -> wlds[(c*NCLASSES + l)*MS + m]
    for (int i = tid; i < NCLASSES * MS * NC; i += 256) {
        int l = i / (MS * NC);
        int r = i - l * (MS * NC);
        int m = r / NC;
        int c = r - m * NC;
        wlds[(c * NCLASSES + l) * MS + m] = Wg[i];
    }
    if (tid < NCLASSES * MS) blds[tid] = bg[tid];
    __syncthreads();

    const int p = blockIdx.x * 256 + tid;
    if (p >= n_pix) return;

    const int bidx = p / HW;
    const int hw   = p - bidx * HW;

    const int lab = clusters[p];
    const bool valid = (lab >= 0) && (lab < NCLASSES);
    const int l = valid ? lab : 0;

    float acc[MS];
#pragma unroll
    for (int m = 0; m < MS; ++m) acc[m] = blds[l * MS + m];

    const float* ip = image + (size_t)bidx * NC * HW + hw;

#pragma unroll 8
    for (int c = 0; c < NC; ++c) {
        const float v = ip[(size_t)c * HW];
        const float4* wp = (const float4*)&wlds[(c * NCLASSES + l) * MS];
        const float4 w0 = wp[0];
        const float4 w1 = wp[1];
        acc[0] = fmaf(v, w0.x, acc[0]);
        acc[1] = fmaf(v, w0.y, acc[1]);
        acc[2] = fmaf(v, w0.z, acc[2]);
        acc[3] = fmaf(v, w0.w, acc[3]);
        acc[4] = fmaf(v, w1.x, acc[4]);
        acc[5] = fmaf(v, w1.y, acc[5]);
        acc[6] = fmaf(v, w1.z, acc[6]);
        acc[7] = fmaf(v, w1.w, acc[7]);
    }

    float* op = out + (size_t)bidx * MS * HW + hw;
#pragma unroll
    for (int m = 0; m < MS; ++m) {
        const float r = valid ? fmaxf(acc[m], 0.0f) : 0.0f;
        op[(size_t)m * HW] = r;
    }
}

extern "C" void kernel_launch(void* const* d_in, const int* in_sizes, int n_in,
                              void* d_out, int out_size, void* d_ws, size_t ws_size,
                              hipStream_t stream) {
    const float* image    = (const float*)d_in[0];
    const int* clusters   = (const int*)d_in[1];
    const float* Wg       = (const float*)d_in[2];
    const float* bg       = (const float*)d_in[3];
    float* out            = (float*)d_out;

    const int n_pix = in_sizes[1]; // B*H*W (clusters element count)
    const int block = 256;
    const int grid  = (n_pix + block - 1) / block;

    clusterdown_kernel<<<grid, block, 0, stream>>>(image, clusters, Wg, bg, out, n_pix);
}